// Round 2
// 428.657 us; speedup vs baseline: 1.0290x; 1.0290x over previous
//
#include <hip/hip_runtime.h>

// DigitCaps matvec: u_hat[b,r,c,o] = sum_i W[r,c,o,i]*x[b,r,i] + bias[o]
// B=512 R=1152 C=10 O=16 I=8. All tensors FLOAT32.
//
// R2 theory: kernel (~199us of the 441us; the other ~242us is the harness
// poison-fill, which itself sustains 6.2 TB/s on this buffer) ran at only
// ~2.1 TB/s because each block iteration scattered 8x 640B chunks at 737KB
// stride (groups owned different b). This version transposes the mapping:
// the 8 groups of a block own 8 CONSECUTIVE r rows, so each block iteration
// stores 5120 contiguous bytes (1024B per wave, full lines), and consecutive
// blocks cover adjacent r-chunks -> collectively contiguous 737KB spans per b.
// W stays register-resident (depends only on r, fixed per thread), reused
// over NB=16 batches. Output uses nontemporal stores (write-once, keeps the
// 5.9MB W resident in L2).
//
// R3 fix: __builtin_nontemporal_store requires a NATIVE vector type, not
// HIP's float4 class -> use ext_vector_type(4) float.

#define B_ 512
#define R_ 1152
#define C_ 10
#define O_ 16
#define I_ 8
#define CO_ 160               // C*O, contiguous inner extent per (b,r)
#define SLOTS 40              // 160 outputs / 4 per thread
#define RPB 8                 // consecutive r rows per block
#define NTHREADS (RPB * SLOTS)   // 320 = 5 waves, zero idle lanes
#define NB 16                 // batches per block (W-frag reuse factor)

typedef float f32x4 __attribute__((ext_vector_type(4)));

__global__ __launch_bounds__(NTHREADS) void digitcaps_kernel(
    const float* __restrict__ x,     // [B,R,I]
    const float* __restrict__ W,     // [R,C,O,I]
    const float* __restrict__ bias,  // [O]
    float* __restrict__ out)         // [B,R,C,O]
{
    const int t  = threadIdx.x;
    const int rr = t / SLOTS;         // r within chunk, 0..7
    const int s  = t - rr * SLOTS;    // slot 0..39: c = s>>2, o-quad = s&3
    const int r  = blockIdx.x * RPB + rr;

    // W fragment for this (r, c, o-quad): 4 rows x 8 i = 32 f32 = 128B contiguous.
    // Flat element offset: ((r*C + c)*O + (s&3)*4)*I = (r*CO_ + s*4)*I
    const f32x4* wp = (const f32x4*)(W + ((size_t)r * CO_ + (size_t)s * 4) * I_);
    float w[4][8];
#pragma unroll
    for (int j = 0; j < 4; ++j) {
        f32x4 lo = wp[2 * j];
        f32x4 hi = wp[2 * j + 1];
        w[j][0] = lo.x; w[j][1] = lo.y; w[j][2] = lo.z; w[j][3] = lo.w;
        w[j][4] = hi.x; w[j][5] = hi.y; w[j][6] = hi.z; w[j][7] = hi.w;
    }

    // bias for this o-quad: 4 f32 = 16B
    f32x4 bv = ((const f32x4*)bias)[s & 3];
    float bsf[4] = {bv.x, bv.y, bv.z, bv.w};

    const int b0 = blockIdx.y * NB;
    const float* xp = x + ((size_t)b0 * R_ + r) * I_;
    // Block's stores per iteration: base + t*16 bytes, t=0..319 -> 5120B contiguous.
    float*       op = out + ((size_t)b0 * R_ + r) * CO_ + (size_t)s * 4;

#pragma unroll 4
    for (int bb = 0; bb < NB; ++bb) {
        // x[b,r,0:8] — two 16B loads, uniform across the 40-lane group (cache broadcast)
        f32x4 xlo = ((const f32x4*)xp)[0];
        f32x4 xhi = ((const f32x4*)xp)[1];
        float xf[8] = {xlo.x, xlo.y, xlo.z, xlo.w, xhi.x, xhi.y, xhi.z, xhi.w};

        float acc[4];
#pragma unroll
        for (int j = 0; j < 4; ++j) acc[j] = bsf[j];
#pragma unroll
        for (int i = 0; i < 8; ++i)
#pragma unroll
            for (int j = 0; j < 4; ++j)
                acc[j] = fmaf(xf[i], w[j][i], acc[j]);

        // 4 contiguous f32 outputs; block iteration = 5120B contiguous stream.
        // Nontemporal: write-once data, don't thrash W out of L2.
        f32x4 ov = {acc[0], acc[1], acc[2], acc[3]};
        __builtin_nontemporal_store(ov, (f32x4*)op);

        xp += (size_t)R_ * I_;
        op += (size_t)R_ * CO_;
    }
}

extern "C" void kernel_launch(void* const* d_in, const int* in_sizes, int n_in,
                              void* d_out, int out_size, void* d_ws, size_t ws_size,
                              hipStream_t stream) {
    const float* x    = (const float*)d_in[0];
    const float* W    = (const float*)d_in[1];
    const float* bias = (const float*)d_in[2];
    float* out        = (float*)d_out;

    dim3 grid(R_ / RPB, B_ / NB);  // (144, 32)
    digitcaps_kernel<<<grid, NTHREADS, 0, stream>>>(x, W, bias, out);
}